// Round 12
// baseline (128.620 us; speedup 1.0000x reference)
//
#include <hip/hip_runtime.h>
#include <hip/hip_bf16.h>
#include <cstdint>
#include <cstddef>

typedef __attribute__((ext_vector_type(8))) __bf16 bf16x8;
typedef __attribute__((ext_vector_type(4))) __bf16 bf16x4;
typedef __attribute__((ext_vector_type(4))) float f32x4;

#define BATCH 4096
#define IN_FEAT 1024
#define OUT_FEAT 1024
#define RNK 16
#define SCALE 2.0f

// ---- kernel 1: a = x@A^T ; x_bf = bf16(x); w_bf = bf16(W_base + 2*(Wc@A)) ----
__global__ __launch_bounds__(256) void prep_kernel(
    const float* __restrict__ x, const float* __restrict__ A,
    const float* __restrict__ W, const float* __restrict__ Wc,
    float* __restrict__ a_out, __bf16* __restrict__ x_bf,
    __bf16* __restrict__ w_bf)
{
    __shared__ float xs[IN_FEAT];
    const int b = blockIdx.x;
    const int t = threadIdx.x;
    const int k0 = t * 4;

    if (b < OUT_FEAT) {
        float4 wv = *reinterpret_cast<const float4*>(&W[(size_t)b * IN_FEAT + k0]);
        float cx = 0.f, cy = 0.f, cz = 0.f, cw = 0.f;
        #pragma unroll
        for (int r = 0; r < RNK; ++r) {
            const float wcr = Wc[b * RNK + r];   // block-uniform -> scalar load
            const float4 av = *reinterpret_cast<const float4*>(&A[r * IN_FEAT + k0]);
            cx += wcr * av.x; cy += wcr * av.y; cz += wcr * av.z; cw += wcr * av.w;
        }
        bf16x4 hw;
        hw[0] = (__bf16)(wv.x + SCALE * cx);
        hw[1] = (__bf16)(wv.y + SCALE * cy);
        hw[2] = (__bf16)(wv.z + SCALE * cz);
        hw[3] = (__bf16)(wv.w + SCALE * cw);
        *reinterpret_cast<bf16x4*>(&w_bf[(size_t)b * IN_FEAT + k0]) = hw;
    }

    const float4 v = *reinterpret_cast<const float4*>(&x[(size_t)b * IN_FEAT + k0]);
    xs[k0 + 0] = v.x; xs[k0 + 1] = v.y; xs[k0 + 2] = v.z; xs[k0 + 3] = v.w;
    bf16x4 h;
    h[0] = (__bf16)v.x; h[1] = (__bf16)v.y; h[2] = (__bf16)v.z; h[3] = (__bf16)v.w;
    *reinterpret_cast<bf16x4*>(&x_bf[(size_t)b * IN_FEAT + k0]) = h;
    __syncthreads();

    const int r = t >> 4;
    const int l16 = t & 15;
    const float* __restrict__ Ar = &A[r * IN_FEAT];
    float s = 0.f;
    #pragma unroll 8
    for (int j = 0; j < IN_FEAT / 16; ++j) {
        const int k = l16 + 16 * j;
        s += xs[k] * Ar[k];
    }
    s += __shfl_xor(s, 8);
    s += __shfl_xor(s, 4);
    s += __shfl_xor(s, 2);
    s += __shfl_xor(s, 1);
    if (l16 == 0) a_out[b * RNK + r] = s;
}

// ---- kernel 2: fused GEMM + 8KB-sequential row gathers (BN=128, 8 waves) ----
#define BM 64
#define BN 128
#define BK 64
#define LDK 72      // bf16 row stride: pads the 128B-stride bank conflict
#define LSTRIDE 132 // lora_s fp32 row stride: breaks 4-way epilogue alias

__global__ __launch_bounds__(512) void fused_kernel(
    const __bf16* __restrict__ x_bf, const __bf16* __restrict__ w_bf,
    const float* __restrict__ a_buf,
    const int* __restrict__ uidx, const int* __restrict__ iidx,
    const float* __restrict__ b_base,
    const float* __restrict__ B_user, const float* __restrict__ B_item,
    float* __restrict__ out)
{
    __shared__ __align__(16) __bf16 xs[BM * LDK];        // 9.2 KB
    __shared__ __align__(16) __bf16 wsh[BN * LDK];       // 18.4 KB
    __shared__ __align__(16) float a_s[BM * RNK];        // 4 KB
    __shared__ __align__(16) float lora_s[BM * LSTRIDE]; // 33.8 KB
    __shared__ int u_s[BM];
    __shared__ int i_s[BM];                              // ~66 KB -> 2 blocks/CU

    const int t = threadIdx.x;

    // XCD swizzle: 512 blocks, 64 contiguous per XCD (8 panels x 8 o-tiles).
    const int bid = blockIdx.y * gridDim.x + blockIdx.x;   // 0..511
    const int nid = (bid & 7) * 64 + (bid >> 3);
    const int o0 = (nid & 7) * BN;
    const int b0 = (nid >> 3) * BM;

    if (t < BM) {
        u_s[t] = uidx[b0 + t];
        i_s[t] = iidx[b0 + t];
    }
    if (t < 256) {
        *reinterpret_cast<float4*>(&a_s[t * 4]) =
            *reinterpret_cast<const float4*>(&a_buf[(size_t)b0 * RNK + t * 4]);
    }

    const int w  = t >> 6;          // wave 0..7
    const int wr = w >> 2;          // wave row (2 x 32 rows)
    const int wc = w & 3;           // wave col (4 x 32 cols)
    const int l  = t & 63;
    const int lr = l & 15;
    const int lg = l >> 4;

    // staging maps (512 threads)
    const int xrow = t >> 3;            // 0..63
    const int xoff = (t & 7) * 8;       // one uint4 (16B)
    const int wrow = t >> 2;            // 0..127
    const int woff = (t & 3) * 16;      // two uint4 (32B)

    f32x4 acc[2][2] = {};

    #pragma unroll
    for (int kt = 0; kt < IN_FEAT / BK; ++kt) {   // 16 iterations, fully unrolled
        __syncthreads();   // all waves done reading previous tile
        // ---- stage K-tile of x (64 rows) and W (128 rows) into LDS ----
        {
            const uint4* g = reinterpret_cast<const uint4*>(
                &x_bf[(size_t)(b0 + xrow) * IN_FEAT + kt * BK + xoff]);
            uint4 v0 = g[0];
            *reinterpret_cast<uint4*>(&xs[xrow * LDK + xoff]) = v0;
            const uint4* gw = reinterpret_cast<const uint4*>(
                &w_bf[(size_t)(o0 + wrow) * IN_FEAT + kt * BK + woff]);
            uint4 w0 = gw[0], w1 = gw[1];
            *reinterpret_cast<uint4*>(&wsh[wrow * LDK + woff]) = w0;
            *reinterpret_cast<uint4*>(&wsh[wrow * LDK + woff + 8]) = w1;
        }
        __syncthreads();   // tile kt visible

        // ==== gather: wave w owns batch row w*8+(kt>>1); even slot reads cols
        // 0..63, odd slot cols 64..127 of the SAME row -> consecutive slots
        // sweep one 8KB-sequential region per table. Loads fly under MFMAs.
        const int grow = w * 8 + (kt >> 1);          // 0..63, each row twice
        const int gcol = (kt & 1) * 64 + l;          // 0..127
        const size_t u  = (size_t)u_s[grow];
        const size_t iv = (size_t)i_s[grow];
        const f32x4* bu = reinterpret_cast<const f32x4*>(
            &B_user[(u * OUT_FEAT + (size_t)(o0 + gcol)) * RNK]);
        const f32x4* bi = reinterpret_cast<const f32x4*>(
            &B_item[(iv * OUT_FEAT + (size_t)(o0 + gcol)) * RNK]);
        f32x4 gu0 = bu[0], gu1 = bu[1], gu2 = bu[2], gu3 = bu[3];
        f32x4 gi0 = bi[0], gi1 = bi[1], gi2 = bi[2], gi3 = bi[3];

        // ---- MFMA on the staged K-tile (wave quadrant 32x32) ----
        #pragma unroll
        for (int kk = 0; kk < BK; kk += 32) {
            bf16x8 af0 = *reinterpret_cast<const bf16x8*>(&xs[(wr * 32 + 0 + lr) * LDK + kk + lg * 8]);
            bf16x8 af1 = *reinterpret_cast<const bf16x8*>(&xs[(wr * 32 + 16 + lr) * LDK + kk + lg * 8]);
            bf16x8 bf0 = *reinterpret_cast<const bf16x8*>(&wsh[(wc * 32 + 0 + lr) * LDK + kk + lg * 8]);
            bf16x8 bf1 = *reinterpret_cast<const bf16x8*>(&wsh[(wc * 32 + 16 + lr) * LDK + kk + lg * 8]);
            acc[0][0] = __builtin_amdgcn_mfma_f32_16x16x32_bf16(af0, bf0, acc[0][0], 0, 0, 0);
            acc[0][1] = __builtin_amdgcn_mfma_f32_16x16x32_bf16(af0, bf1, acc[0][1], 0, 0, 0);
            acc[1][0] = __builtin_amdgcn_mfma_f32_16x16x32_bf16(af1, bf0, acc[1][0], 0, 0, 0);
            acc[1][1] = __builtin_amdgcn_mfma_f32_16x16x32_bf16(af1, bf1, acc[1][1], 0, 0, 0);
        }

        // ---- gather consume: lane owns (row grow, col o0+gcol) ----
        {
            const f32x4* av4 = reinterpret_cast<const f32x4*>(&a_s[grow * RNK]);  // broadcast
            float lora = 0.f;
            const f32x4 s0 = gu0 + gi0, a0 = av4[0];
            lora += s0[0]*a0[0] + s0[1]*a0[1] + s0[2]*a0[2] + s0[3]*a0[3];
            const f32x4 s1 = gu1 + gi1, a1 = av4[1];
            lora += s1[0]*a1[0] + s1[1]*a1[1] + s1[2]*a1[2] + s1[3]*a1[3];
            const f32x4 s2 = gu2 + gi2, a2 = av4[2];
            lora += s2[0]*a2[0] + s2[1]*a2[1] + s2[2]*a2[2] + s2[3]*a2[3];
            const f32x4 s3 = gu3 + gi3, a3 = av4[3];
            lora += s3[0]*a3[0] + s3[1]*a3[1] + s3[2]*a3[2] + s3[3]*a3[3];
            lora_s[grow * LSTRIDE + gcol] = SCALE * lora;   // lane-contiguous
        }
    }

    __syncthreads();   // lora_s complete

    // ---- write-out: base(+common) + bias + lora from LDS ----
    #pragma unroll
    for (int n = 0; n < 2; ++n) {
        const int ol = wc * 32 + n * 16 + lr;
        const int o  = o0 + ol;
        const float bb = b_base[o];
        #pragma unroll
        for (int m = 0; m < 2; ++m) {
            #pragma unroll
            for (int i = 0; i < 4; ++i) {
                const int bl2 = wr * 32 + m * 16 + lg * 4 + i;
                out[(size_t)(b0 + bl2) * OUT_FEAT + o] =
                    acc[m][n][i] + bb + lora_s[bl2 * LSTRIDE + ol];
            }
        }
    }
}

extern "C" void kernel_launch(void* const* d_in, const int* in_sizes, int n_in,
                              void* d_out, int out_size, void* d_ws, size_t ws_size,
                              hipStream_t stream) {
    const float* x        = (const float*)d_in[0];
    const int*   uidx     = (const int*)d_in[1];
    const int*   iidx     = (const int*)d_in[2];
    const float* W_base   = (const float*)d_in[3];
    const float* b_base   = (const float*)d_in[4];
    const float* A        = (const float*)d_in[5];
    const float* B_user   = (const float*)d_in[6];
    const float* B_item   = (const float*)d_in[7];
    const float* W_common = (const float*)d_in[8];
    float* out = (float*)d_out;

    float*  a_buf = (float*)d_ws;                                     // 256 KB
    __bf16* x_bf  = (__bf16*)((char*)d_ws + (256 << 10));             // 8 MB
    __bf16* w_bf  = (__bf16*)((char*)d_ws + (256 << 10) + (8 << 20)); // 2 MB

    prep_kernel<<<BATCH, 256, 0, stream>>>(x, A, W_base, W_common, a_buf, x_bf, w_bf);

    dim3 grid(OUT_FEAT / BN, BATCH / BM);
    fused_kernel<<<grid, 512, 0, stream>>>(x_bf, w_bf, a_buf, uidx, iidx,
                                           b_base, B_user, B_item, out);
}

// Round 13
// 122.070 us; speedup vs baseline: 1.0537x; 1.0537x over previous
//
#include <hip/hip_runtime.h>
#include <hip/hip_bf16.h>
#include <cstdint>
#include <cstddef>

typedef __attribute__((ext_vector_type(8))) __bf16 bf16x8;
typedef __attribute__((ext_vector_type(4))) __bf16 bf16x4;
typedef __attribute__((ext_vector_type(4))) float f32x4;

#define BATCH 4096
#define IN_FEAT 1024
#define OUT_FEAT 1024
#define RNK 16
#define SCALE 2.0f

// ---- kernel 1: a = x@A^T ; x_bf = bf16(x); w_bf = bf16(W_base + 2*(Wc@A)) ----
// common_part = a @ Wc^T = x @ (Wc@A)^T  -> folded into the base GEMM weights.
__global__ __launch_bounds__(256) void prep_kernel(
    const float* __restrict__ x, const float* __restrict__ A,
    const float* __restrict__ W, const float* __restrict__ Wc,
    float* __restrict__ a_out, __bf16* __restrict__ x_bf,
    __bf16* __restrict__ w_bf)
{
    __shared__ float xs[IN_FEAT];
    const int b = blockIdx.x;
    const int t = threadIdx.x;
    const int k0 = t * 4;

    if (b < OUT_FEAT) {
        float4 wv = *reinterpret_cast<const float4*>(&W[(size_t)b * IN_FEAT + k0]);
        float cx = 0.f, cy = 0.f, cz = 0.f, cw = 0.f;
        #pragma unroll
        for (int r = 0; r < RNK; ++r) {
            const float wcr = Wc[b * RNK + r];   // block-uniform -> scalar load
            const float4 av = *reinterpret_cast<const float4*>(&A[r * IN_FEAT + k0]);
            cx += wcr * av.x; cy += wcr * av.y; cz += wcr * av.z; cw += wcr * av.w;
        }
        bf16x4 hw;
        hw[0] = (__bf16)(wv.x + SCALE * cx);
        hw[1] = (__bf16)(wv.y + SCALE * cy);
        hw[2] = (__bf16)(wv.z + SCALE * cz);
        hw[3] = (__bf16)(wv.w + SCALE * cw);
        *reinterpret_cast<bf16x4*>(&w_bf[(size_t)b * IN_FEAT + k0]) = hw;
    }

    const float4 v = *reinterpret_cast<const float4*>(&x[(size_t)b * IN_FEAT + k0]);
    xs[k0 + 0] = v.x; xs[k0 + 1] = v.y; xs[k0 + 2] = v.z; xs[k0 + 3] = v.w;
    bf16x4 h;
    h[0] = (__bf16)v.x; h[1] = (__bf16)v.y; h[2] = (__bf16)v.z; h[3] = (__bf16)v.w;
    *reinterpret_cast<bf16x4*>(&x_bf[(size_t)b * IN_FEAT + k0]) = h;
    __syncthreads();

    const int r = t >> 4;
    const int l16 = t & 15;
    const float* __restrict__ Ar = &A[r * IN_FEAT];
    float s = 0.f;
    #pragma unroll 8
    for (int j = 0; j < IN_FEAT / 16; ++j) {
        const int k = l16 + 16 * j;
        s += xs[k] * Ar[k];
    }
    s += __shfl_xor(s, 8);
    s += __shfl_xor(s, 4);
    s += __shfl_xor(s, 2);
    s += __shfl_xor(s, 1);
    if (l16 == 0) a_out[b * RNK + r] = s;
}

// ---- kernel 2: fused GEMM + 4KB-contiguous row gathers (page-local) ----
#define BM 64
#define BN 64
#define BK 64
#define LDK 72   // +8 bf16 pad: breaks the 128B-stride bank conflict

__global__ __launch_bounds__(256) void fused_kernel(
    const __bf16* __restrict__ x_bf, const __bf16* __restrict__ w_bf,
    const float* __restrict__ a_buf,
    const int* __restrict__ uidx, const int* __restrict__ iidx,
    const float* __restrict__ b_base,
    const float* __restrict__ B_user, const float* __restrict__ B_item,
    float* __restrict__ out)
{
    __shared__ __align__(16) __bf16 xs[BM * LDK];       // 9.2 KB
    __shared__ __align__(16) __bf16 wsh[BN * LDK];      // 9.2 KB
    __shared__ __align__(16) float a_s[BM * RNK];       // 4 KB
    __shared__ __align__(16) float lora_s[BM * BN];     // 16 KB
    __shared__ int u_s[BM];
    __shared__ int i_s[BM];                             // total ~39.4 KB -> 4 blocks/CU

    const int t = threadIdx.x;

    // XCD-aware bijective swizzle: 1024 blocks, 128 contiguous per XCD.
    const int bid = blockIdx.y * gridDim.x + blockIdx.x;
    const int nid = (bid & 7) * 128 + (bid >> 3);
    const int o0 = (nid & 15) * BN;
    const int b0 = (nid >> 4) * BM;

    if (t < BM) {
        u_s[t] = uidx[b0 + t];
        i_s[t] = iidx[b0 + t];
    }
    *reinterpret_cast<float4*>(&a_s[t * 4]) =
        *reinterpret_cast<const float4*>(&a_buf[(size_t)b0 * RNK + t * 4]);

    const int w  = t >> 6;
    const int wr = w >> 1;
    const int wc = w & 1;
    const int l  = t & 63;
    const int lr = l & 15;
    const int lg = l >> 4;

    const int srow  = t >> 2;
    const int skoff = (t & 3) * 16;

    f32x4 acc[2][2] = {};

    #pragma unroll
    for (int kt = 0; kt < IN_FEAT / BK; ++kt) {   // 16 iterations, fully unrolled
        __syncthreads();   // all waves done reading previous tile
        // ---- stage K-tile of x and W into LDS ----
        {
            const uint4* g = reinterpret_cast<const uint4*>(
                &x_bf[(size_t)(b0 + srow) * IN_FEAT + kt * BK + skoff]);
            uint4 v0 = g[0], v1 = g[1];
            *reinterpret_cast<uint4*>(&xs[srow * LDK + skoff]) = v0;
            *reinterpret_cast<uint4*>(&xs[srow * LDK + skoff + 8]) = v1;
            const uint4* gw = reinterpret_cast<const uint4*>(
                &w_bf[(size_t)(o0 + srow) * IN_FEAT + kt * BK + skoff]);
            uint4 w0 = gw[0], w1 = gw[1];
            *reinterpret_cast<uint4*>(&wsh[srow * LDK + skoff]) = w0;
            *reinterpret_cast<uint4*>(&wsh[srow * LDK + skoff + 8]) = w1;
        }
        __syncthreads();   // tile kt visible

        // ==== gather issue: wave w handles batch row bl = w*16 + kt. The 64
        // lanes read consecutive output-cols o0+l of B[u] -> ONE contiguous
        // 4KB region per table (page-local). Loads complete under the MFMAs.
        const int bl = w * 16 + kt;                  // wave-uniform, 0..63 bijective
        const size_t u  = (size_t)u_s[bl];
        const size_t iv = (size_t)i_s[bl];
        const f32x4* bu = reinterpret_cast<const f32x4*>(
            &B_user[(u * OUT_FEAT + (size_t)(o0 + l)) * RNK]);
        const f32x4* bi = reinterpret_cast<const f32x4*>(
            &B_item[(iv * OUT_FEAT + (size_t)(o0 + l)) * RNK]);
        f32x4 gu0 = bu[0], gu1 = bu[1], gu2 = bu[2], gu3 = bu[3];
        f32x4 gi0 = bi[0], gi1 = bi[1], gi2 = bi[2], gi3 = bi[3];

        // ---- MFMA on the staged K-tile ----
        #pragma unroll
        for (int kk = 0; kk < BK; kk += 32) {
            bf16x8 af0 = *reinterpret_cast<const bf16x8*>(&xs[(wr * 32 + 0 + lr) * LDK + kk + lg * 8]);
            bf16x8 af1 = *reinterpret_cast<const bf16x8*>(&xs[(wr * 32 + 16 + lr) * LDK + kk + lg * 8]);
            bf16x8 bf0 = *reinterpret_cast<const bf16x8*>(&wsh[(wc * 32 + 0 + lr) * LDK + kk + lg * 8]);
            bf16x8 bf1 = *reinterpret_cast<const bf16x8*>(&wsh[(wc * 32 + 16 + lr) * LDK + kk + lg * 8]);
            acc[0][0] = __builtin_amdgcn_mfma_f32_16x16x32_bf16(af0, bf0, acc[0][0], 0, 0, 0);
            acc[0][1] = __builtin_amdgcn_mfma_f32_16x16x32_bf16(af0, bf1, acc[0][1], 0, 0, 0);
            acc[1][0] = __builtin_amdgcn_mfma_f32_16x16x32_bf16(af1, bf0, acc[1][0], 0, 0, 0);
            acc[1][1] = __builtin_amdgcn_mfma_f32_16x16x32_bf16(af1, bf1, acc[1][1], 0, 0, 0);
        }

        // ---- gather consume: lane l owns (row bl, col o0+l) ----
        {
            const f32x4* av4 = reinterpret_cast<const f32x4*>(&a_s[bl * RNK]);  // broadcast
            float lora = 0.f;
            const f32x4 s0 = gu0 + gi0, a0 = av4[0];
            lora += s0[0]*a0[0] + s0[1]*a0[1] + s0[2]*a0[2] + s0[3]*a0[3];
            const f32x4 s1 = gu1 + gi1, a1 = av4[1];
            lora += s1[0]*a1[0] + s1[1]*a1[1] + s1[2]*a1[2] + s1[3]*a1[3];
            const f32x4 s2 = gu2 + gi2, a2 = av4[2];
            lora += s2[0]*a2[0] + s2[1]*a2[1] + s2[2]*a2[2] + s2[3]*a2[3];
            const f32x4 s3 = gu3 + gi3, a3 = av4[3];
            lora += s3[0]*a3[0] + s3[1]*a3[1] + s3[2]*a3[2] + s3[3]*a3[3];
            lora_s[bl * BN + l] = SCALE * lora;    // lane-contiguous, conflict-free
        }
    }

    __syncthreads();   // lora_s complete (rows written by other waves)

    // ---- write-out: base(+common) + bias + lora from LDS ----
    #pragma unroll
    for (int n = 0; n < 2; ++n) {
        const int ol = wc * 32 + n * 16 + lr;
        const int o  = o0 + ol;
        const float bb = b_base[o];
        #pragma unroll
        for (int m = 0; m < 2; ++m) {
            #pragma unroll
            for (int i = 0; i < 4; ++i) {
                const int bl2 = wr * 32 + m * 16 + lg * 4 + i;
                out[(size_t)(b0 + bl2) * OUT_FEAT + o] =
                    acc[m][n][i] + bb + lora_s[bl2 * BN + ol];
            }
        }
    }
}

extern "C" void kernel_launch(void* const* d_in, const int* in_sizes, int n_in,
                              void* d_out, int out_size, void* d_ws, size_t ws_size,
                              hipStream_t stream) {
    const float* x        = (const float*)d_in[0];
    const int*   uidx     = (const int*)d_in[1];
    const int*   iidx     = (const int*)d_in[2];
    const float* W_base   = (const float*)d_in[3];
    const float* b_base   = (const float*)d_in[4];
    const float* A        = (const float*)d_in[5];
    const float* B_user   = (const float*)d_in[6];
    const float* B_item   = (const float*)d_in[7];
    const float* W_common = (const float*)d_in[8];
    float* out = (float*)d_out;

    float*  a_buf = (float*)d_ws;                                     // 256 KB
    __bf16* x_bf  = (__bf16*)((char*)d_ws + (256 << 10));             // 8 MB
    __bf16* w_bf  = (__bf16*)((char*)d_ws + (256 << 10) + (8 << 20)); // 2 MB

    prep_kernel<<<BATCH, 256, 0, stream>>>(x, A, W_base, W_common, a_buf, x_bf, w_bf);

    dim3 grid(OUT_FEAT / BN, BATCH / BM);
    fused_kernel<<<grid, 256, 0, stream>>>(x_bf, w_bf, a_buf, uidx, iidx,
                                           b_base, B_user, B_item, out);
}